// Round 4
// baseline (3001.695 us; speedup 1.0000x reference)
//
#include <hip/hip_runtime.h>
#include <stdint.h>

#define BETA 0.9f

typedef unsigned short u16;
typedef unsigned char u8;
typedef _Float16 f16x8 __attribute__((ext_vector_type(8)));
typedef float f32x4 __attribute__((ext_vector_type(4)));

// ---------------------------------------------------------------------------
// prep: fp16 2-split of W2/W3 with scale folded for exponent-only B values:
//   hi chunk stores f16(w)*0.5          (B bit -> 2.0)
//   mid chunk stores f16((w-f16(w))*2048) (B bit -> 2^-11; 2048*2^-11 = 1)
// Layout A[chunk][tap][co][ci32], chunk-major contiguous.
// Also transpose fc weights.
// ---------------------------------------------------------------------------
__global__ void prep_kernel(const float* __restrict__ W2, const float* __restrict__ W3,
                            const float* __restrict__ fw1, const float* __restrict__ fw2,
                            u16* __restrict__ A2c, u16* __restrict__ A3c,
                            float* __restrict__ fw1T, float* __restrict__ fw2T) {
  int o = blockIdx.x * 256 + threadIdx.x;
  if (o < 98304) {  // W2: (tap, co, ci), 3*128*256
    int tap = o >> 15, r = o & 32767, co = r >> 8, ci = r & 255;
    float w = W2[(co * 256 + ci) * 3 + tap];
    float h = (float)(_Float16)w;
    _Float16 hv = (_Float16)(h * 0.5f);
    _Float16 mv = (_Float16)((w - h) * 2048.0f);
    u16 hb, mb;
    __builtin_memcpy(&hb, &hv, 2);
    __builtin_memcpy(&mb, &mv, 2);
    int c = ci >> 5, cl = ci & 31;
    A2c[((c * 3 + tap) * 128 + co) * 32 + cl] = hb;
    A2c[(((c + 8) * 3 + tap) * 128 + co) * 32 + cl] = mb;
  }
  int o2 = o - 98304;  // W3: (tap, co, ci), 3*64*128
  if (o2 >= 0 && o2 < 24576) {
    int tap = o2 >> 13, r = o2 & 8191, co = r >> 7, ci = r & 127;
    float w = W3[(co * 128 + ci) * 3 + tap];
    float h = (float)(_Float16)w;
    _Float16 hv = (_Float16)(h * 0.5f);
    _Float16 mv = (_Float16)((w - h) * 2048.0f);
    u16 hb, mb;
    __builtin_memcpy(&hb, &hv, 2);
    __builtin_memcpy(&mb, &mv, 2);
    int c = ci >> 5, cl = ci & 31;
    A3c[((c * 3 + tap) * 64 + co) * 32 + cl] = hb;
    A3c[(((c + 4) * 3 + tap) * 64 + co) * 32 + cl] = mb;
  }
  int o3 = o - (98304 + 24576);
  if (o3 >= 0 && o3 < 25600) {
    int f = o3 / 100, i = o3 % 100;
    fw1T[o3] = fw1[i * 256 + f];
  }
  int o4 = o - (98304 + 24576 + 25600);
  if (o4 >= 0 && o4 < 4000) {
    int i = o4 / 40, j = o4 % 40;
    fw2T[o4] = fw2[j * 100 + i];
  }
}

// ---------------------------------------------------------------------------
// conv1 (2->256, K=5, pad=2) + LIF1; writes byte-transposed spike layout
// SBT2[b][l][g][t] (byte = spikes of co in [8g,8g+8), bit j = co 8g+j).
// Block: (b, g). cur constant across t.
// ---------------------------------------------------------------------------
__global__ __launch_bounds__(256) void conv1_lif_kernel(
    const float* __restrict__ x, const float* __restrict__ W1,
    const float* __restrict__ b1, u8* __restrict__ SBT2) {
  __shared__ float xl[2][132];
  __shared__ u16 bl[8][128];
  int b = blockIdx.x, g = blockIdx.y;
  int tid = threadIdx.x;
  for (int i = tid; i < 264; i += 256) {
    int ci = i / 132, idx = i % 132, lg = idx - 2;
    xl[ci][idx] = (lg >= 0 && lg < 128) ? x[(b * 2 + ci) * 128 + lg] : 0.0f;
  }
  __syncthreads();
  int cosub = tid >> 5, tx = tid & 31;
  int co = g * 8 + cosub;
  float w[2][5];
#pragma unroll
  for (int ci = 0; ci < 2; ++ci)
#pragma unroll
    for (int k = 0; k < 5; ++k) w[ci][k] = W1[(co * 2 + ci) * 5 + k];
  float bias = b1[co];
  float cur[4];
#pragma unroll
  for (int j = 0; j < 4; ++j) {
    float acc = bias;
#pragma unroll
    for (int ci = 0; ci < 2; ++ci)
#pragma unroll
      for (int k = 0; k < 5; ++k) acc += w[ci][k] * xl[ci][4 * tx + j + k];
    cur[j] = acc;
  }
  float m[4] = {0.f, 0.f, 0.f, 0.f}, sp[4] = {0.f, 0.f, 0.f, 0.f};
  uint32_t bits[4] = {0u, 0u, 0u, 0u};
#pragma unroll
  for (int t = 0; t < 16; ++t) {
#pragma unroll
    for (int j = 0; j < 4; ++j) {
      m[j] = BETA * m[j] + cur[j] - sp[j];
      bool s = m[j] > 1.0f;
      bits[j] |= ((uint32_t)s) << t;
      sp[j] = s ? 1.0f : 0.0f;
    }
  }
#pragma unroll
  for (int j = 0; j < 4; ++j) bl[cosub][4 * tx + j] = (u16)bits[j];
  __syncthreads();
  if (tid < 128) {
    int l = tid;
    uint32_t wv[8];
#pragma unroll
    for (int j = 0; j < 8; ++j) wv[j] = bl[j][l];
    uint32_t ov[4];
#pragma unroll
    for (int k = 0; k < 4; ++k) {
      uint32_t v = 0;
#pragma unroll
      for (int tt = 0; tt < 4; ++tt) {
        int t = k * 4 + tt;
        uint32_t by = 0;
#pragma unroll
        for (int j = 0; j < 8; ++j) by |= ((wv[j] >> t) & 1u) << j;
        v |= by << (8 * tt);
      }
      ov[k] = v;
    }
    *(uint4*)(SBT2 + ((size_t)(b * 128 + l) * 32 + g) * 16) =
        make_uint4(ov[0], ov[1], ov[2], ov[3]);
  }
}

// ---------------------------------------------------------------------------
// repack: u16 spike words [b][ci][l] -> byte-transposed [b][l][ci/8][t]
// ---------------------------------------------------------------------------
__global__ __launch_bounds__(256) void repack128_kernel(
    const u16* __restrict__ sin, u8* __restrict__ sbt) {
  int idx = blockIdx.x * 256 + threadIdx.x;  // b * 2048 + g * 128 + l
  int l = idx & 127, r = idx >> 7, g = r & 15, b = r >> 4;
  const u16* p = sin + ((size_t)b * 128 + g * 8) * 128 + l;
  uint32_t wv[8];
#pragma unroll
  for (int j = 0; j < 8; ++j) wv[j] = p[j * 128];
  uint32_t ov[4];
#pragma unroll
  for (int k = 0; k < 4; ++k) {
    uint32_t v = 0;
#pragma unroll
    for (int tt = 0; tt < 4; ++tt) {
      int t = k * 4 + tt;
      uint32_t by = 0;
#pragma unroll
      for (int j = 0; j < 8; ++j) by |= ((wv[j] >> t) & 1u) << j;
      v |= by << (8 * tt);
    }
    ov[k] = v;
  }
  *(uint4*)(sbt + ((size_t)(b * 128 + l) * 16 + g) * 16) =
      make_uint4(ov[0], ov[1], ov[2], ov[3]);
}

// ---------------------------------------------------------------------------
// Streaming MFMA conv (CIN->COUT, K=3, pad=1) + LIF. No LDS in the K-loop:
// A fragments stream per-lane from L1 (chunk working set 24KB), B fragments
// are single-byte loads from SBT expanded in-register (bit -> 2.0 for hi
// chunks / 2^-11 for mid chunks; scales pre-folded into A).
// Block: b x 16 l x all COUT. Waves 2x2 (wy m-half, wx n-half of 8 ll).
// ---------------------------------------------------------------------------
__device__ __forceinline__ f16x8 expandB(uint32_t byte, int P) {
  union { uint32_t u[4]; f16x8 v; } r;
#pragma unroll
  for (int mm = 0; mm < 4; ++mm) {
    uint32_t b0 = (byte >> (2 * mm)) & 1u;
    uint32_t b1 = (byte >> (2 * mm + 1)) & 1u;
    r.u[mm] = (b0 << P) | (b1 << (P + 16));
  }
  return r.v;
}

template <int CIN, int COUT>
__global__ __launch_bounds__(256, 2) void conv_mfma_kernel(
    const u8* __restrict__ SBT, const u16* __restrict__ Agc,
    const float* __restrict__ bias, u16* __restrict__ sbits_out) {
  constexpr int NCHUNK = CIN / 16;  // virtual K chunks (hi + mid)
  constexpr int HC = CIN / 32;      // hi chunk count
  constexpr int MT = COUT / 32;     // m-tiles per wave
  constexpr int GB = CIN / 8;       // byte groups per (b,l) row
  __shared__ float scr_all[4][4 * 16 * 18];

  int b = blockIdx.x, lb = blockIdx.y * 16;
  int tid = threadIdx.x, lane = tid & 63, wid = tid >> 6;
  int wx = wid & 1, wy = wid >> 1;
  int q = lane >> 4, xx = lane & 15;
  int mbase = wy * (COUT / 2);

  f32x4 acc[MT][8];
#pragma unroll
  for (int mt = 0; mt < MT; ++mt)
#pragma unroll
    for (int nt = 0; nt < 8; ++nt) acc[mt][nt] = (f32x4){0.f, 0.f, 0.f, 0.f};

  const size_t browbase = (size_t)b * 128;
  // preload chunk-0 bytes
  uint32_t byt[10];
#pragma unroll
  for (int u = 0; u < 10; ++u) {
    int l_in = lb + wx * 8 + u - 1;
    uint32_t v = 0;
    if ((unsigned)l_in < 128u) v = SBT[((browbase + l_in) * GB + q) * 16 + xx];
    byt[u] = v;
  }

  for (int c = 0; c < NCHUNK; ++c) {
    // A fragment loads for this chunk (L1-hot, issued before expansions)
    f16x8 Af[3][MT];
#pragma unroll
    for (int tap = 0; tap < 3; ++tap)
#pragma unroll
      for (int mt = 0; mt < MT; ++mt)
        Af[tap][mt] = *(const f16x8*)(Agc +
            (((size_t)(c * 3 + tap) * COUT) + mbase + mt * 16 + xx) * 32 + q * 8);

    // expand current B fragments (scale via exponent-only bit placement)
    int P = (c < HC) ? 14 : 12;
    f16x8 Bf[10];
#pragma unroll
    for (int u = 0; u < 10; ++u) Bf[u] = expandB(byt[u], P);

    // prefetch next chunk's bytes
    int cn = c + 1;
    if (cn < NCHUNK) {
      int g0 = (cn >= HC ? cn - HC : cn) * 4;
#pragma unroll
      for (int u = 0; u < 10; ++u) {
        int l_in = lb + wx * 8 + u - 1;
        uint32_t v = 0;
        if ((unsigned)l_in < 128u)
          v = SBT[((browbase + l_in) * GB + g0 + q) * 16 + xx];
        byt[u] = v;
      }
    }

#pragma unroll
    for (int tap = 0; tap < 3; ++tap)
#pragma unroll
      for (int mt = 0; mt < MT; ++mt)
#pragma unroll
        for (int nt = 0; nt < 8; ++nt)
          acc[mt][nt] = __builtin_amdgcn_mfma_f32_16x16x32_f16(
              Af[tap][mt], Bf[nt + tap], acc[mt][nt], 0, 0, 0);
  }

  // epilogue: transpose per-wave via LDS scratch, LIF, pack u16 bits
  float* scr = scr_all[wid];
#pragma unroll
  for (int mt = 0; mt < MT; ++mt) {
#pragma unroll
    for (int g = 0; g < 2; ++g) {
#pragma unroll
      for (int u2 = 0; u2 < 4; ++u2)
#pragma unroll
        for (int r = 0; r < 4; ++r)
          scr[(u2 * 16 + q * 4 + r) * 18 + xx] = acc[mt][g * 4 + u2][r];
      __syncthreads();
      int co = mbase + mt * 16 + xx;
      int l = lb + wx * 8 + g * 4 + q;
      float bc = bias[co];
      const float* rowp = scr + (q * 16 + xx) * 18;
      float mm = 0.f, sp = 0.f;
      uint32_t bits = 0;
#pragma unroll
      for (int t = 0; t < 16; ++t) {
        float cur = rowp[t] + bc;
        mm = BETA * mm + cur - sp;
        bool s = mm > 1.0f;
        bits |= ((uint32_t)s) << t;
        sp = s ? 1.0f : 0.0f;
      }
      sbits_out[((size_t)b * COUT + co) * 128 + l] = (u16)bits;
      __syncthreads();
    }
  }
}

// ---------------------------------------------------------------------------
// head: conv4 (64->2) + LIF4, fc1 (256->100) + LIF5, fc2 accumulated (popcount)
// ---------------------------------------------------------------------------
__global__ __launch_bounds__(256) void head_kernel(
    const u16* __restrict__ s3bits, const float* __restrict__ W4,
    const float* __restrict__ b4, const float* __restrict__ fw1T,
    const float* __restrict__ fb1, const float* __restrict__ fw2T,
    const float* __restrict__ fb2, float* __restrict__ out) {
  __shared__ u16 s3l[64][130];
  __shared__ float W4l[384];
  __shared__ u16 flat4[256];
  __shared__ u16 s5b[100];
  int b = blockIdx.x, tid = threadIdx.x;

  for (int i = tid; i < 64 * 130; i += 256) {
    int ci = i / 130, idx = i % 130, lg = idx - 1;
    s3l[ci][idx] = (lg >= 0 && lg < 128) ? s3bits[((size_t)b * 64 + ci) * 128 + lg] : (u16)0;
  }
  for (int i = tid; i < 384; i += 256) W4l[i] = W4[i];
  __syncthreads();

  {
    int co = tid >> 7, l = tid & 127;
    float acc4[16];
#pragma unroll
    for (int t = 0; t < 16; ++t) acc4[t] = 0.f;
    for (int ci = 0; ci < 64; ++ci) {
#pragma unroll
      for (int k = 0; k < 3; ++k) {
        float wv = W4l[(co * 64 + ci) * 3 + k];
        uint32_t msk = s3l[ci][l + k];
#pragma unroll
        for (int t = 0; t < 16; ++t)
          acc4[t] = fmaf(wv, (float)((msk >> t) & 1u), acc4[t]);
      }
    }
    float bc = b4[co];
    float m = 0.f, sp = 0.f;
    uint32_t bits = 0;
#pragma unroll
    for (int t = 0; t < 16; ++t) {
      m = BETA * m + (acc4[t] + bc) - sp;
      bool s = m > 1.0f;
      bits |= ((uint32_t)s) << t;
      sp = s ? 1.0f : 0.0f;
    }
    flat4[tid] = (u16)bits;
  }
  __syncthreads();

  if (tid < 100) {
    float acc5[16];
#pragma unroll
    for (int t = 0; t < 16; ++t) acc5[t] = 0.f;
    for (int f = 0; f < 256; ++f) {
      float wv = fw1T[f * 100 + tid];
      uint32_t msk = flat4[f];
#pragma unroll
      for (int t = 0; t < 16; ++t)
        acc5[t] = fmaf(wv, (float)((msk >> t) & 1u), acc5[t]);
    }
    float bc = fb1[tid];
    float m = 0.f, sp = 0.f;
    uint32_t bits = 0;
#pragma unroll
    for (int t = 0; t < 16; ++t) {
      m = BETA * m + (acc5[t] + bc) - sp;
      bool s = m > 1.0f;
      bits |= ((uint32_t)s) << t;
      sp = s ? 1.0f : 0.0f;
    }
    s5b[tid] = (u16)bits;
  }
  __syncthreads();

  if (tid < 40) {
    float a = 0.f;
    for (int i = 0; i < 100; ++i) {
      float wv = fw2T[i * 40 + tid];
      a = fmaf(wv, (float)__popc((uint32_t)s5b[i]), a);
    }
    out[b * 40 + tid] = a * 0.0625f + fb2[tid];
  }
}

// ---------------------------------------------------------------------------
extern "C" void kernel_launch(void* const* d_in, const int* in_sizes, int n_in,
                              void* d_out, int out_size, void* d_ws, size_t ws_size,
                              hipStream_t stream) {
  const float* x   = (const float*)d_in[0];
  const float* W1  = (const float*)d_in[1];
  const float* b1  = (const float*)d_in[2];
  const float* W2  = (const float*)d_in[3];
  const float* b2  = (const float*)d_in[4];
  const float* W3  = (const float*)d_in[5];
  const float* b3  = (const float*)d_in[6];
  const float* W4  = (const float*)d_in[7];
  const float* b4  = (const float*)d_in[8];
  const float* fw1 = (const float*)d_in[9];
  const float* fb1 = (const float*)d_in[10];
  const float* fw2 = (const float*)d_in[11];
  const float* fb2 = (const float*)d_in[12];
  float* out = (float*)d_out;

  char* ws = (char*)d_ws;
  u16*   A2c  = (u16*)(ws);                      // 393216 B [chunk][tap][co][ci32]
  u16*   A3c  = (u16*)(ws + 393216);             //  98304 B
  float* fw1T = (float*)(ws + 491520);           // 102400 B
  float* fw2T = (float*)(ws + 593920);           //  16000 B (pad to 610304)
  u8*    SBT2 = (u8*)(ws + 610304);              // 134217728 B [b][l][32][16]
  u16*   s2b  = (u16*)(ws + 610304 + 134217728); //  67108864 B u16 [b][co][l]
  u8*    SBT3 = SBT2;                            // alias: SBT2 dead after conv2 (67108864 B)
  u16*   s3b  = (u16*)(ws + 610304 + 67108864);  // alias into SBT2 region 2nd half (33.5 MB)
  // total: 201,936,896 B (same footprint as round 3)

  prep_kernel<<<dim3(596), dim3(256), 0, stream>>>(W2, W3, fw1, fw2, A2c, A3c, fw1T, fw2T);
  conv1_lif_kernel<<<dim3(2048, 32), dim3(256), 0, stream>>>(x, W1, b1, SBT2);
  conv_mfma_kernel<256, 128><<<dim3(2048, 8), dim3(256), 0, stream>>>(SBT2, A2c, b2, s2b);
  repack128_kernel<<<dim3(16384), dim3(256), 0, stream>>>(s2b, SBT3);
  conv_mfma_kernel<128, 64><<<dim3(2048, 8), dim3(256), 0, stream>>>(SBT3, A3c, b3, s3b);
  head_kernel<<<dim3(2048), dim3(256), 0, stream>>>(s3b, W4, b4, fw1T, fb1, fw2T, fb2, out);
}

// Round 5
// 2024.967 us; speedup vs baseline: 1.4823x; 1.4823x over previous
//
#include <hip/hip_runtime.h>
#include <stdint.h>

#define BETA 0.9f

typedef unsigned short u16;
typedef unsigned char u8;
typedef _Float16 f16x8 __attribute__((ext_vector_type(8)));
typedef float f32x4 __attribute__((ext_vector_type(4)));

// async global->LDS, 16B per lane; lds ptr is wave-uniform base (+lane*16 by HW)
__device__ __forceinline__ void async_copy16(const void* g, void* l) {
  __builtin_amdgcn_global_load_lds(
      (const __attribute__((address_space(1))) uint32_t*)g,
      (__attribute__((address_space(3))) uint32_t*)l, 16, 0, 0);
}

// byte (8 spike bits) -> f16x8 with value bit * 2^-11 (f16 bits 0x1000)
__device__ __forceinline__ f16x8 expandB(uint32_t byte) {
  union { uint32_t u[4]; f16x8 v; } r;
  uint32_t z = byte | (byte << 15);  // bit 2m at 2m, bit 2m+1 at 2m+16
#pragma unroll
  for (int m = 0; m < 4; ++m)
    r.u[m] = ((z >> (2 * m)) & 0x10001u) << 12;
  return r.v;
}

// ---------------------------------------------------------------------------
// prep: fp16 2-split with scale folded into A (B always contributes 2^-11):
//   hi-part stores f16(f16(w)*2048)   [exact: power-of-2 shift]
//   mid-part stores f16((w-f16(w))*2048)
// Layout A[phys][part][tap][co][ci32], (phys,part) blocks contiguous.
// Also transpose fc weights.
// ---------------------------------------------------------------------------
__global__ void prep_kernel(const float* __restrict__ W2, const float* __restrict__ W3,
                            const float* __restrict__ fw1, const float* __restrict__ fw2,
                            u16* __restrict__ A2c, u16* __restrict__ A3c,
                            float* __restrict__ fw1T, float* __restrict__ fw2T) {
  int o = blockIdx.x * 256 + threadIdx.x;
  if (o < 98304) {  // W2: (tap, co, ci), 3*128*256
    int tap = o >> 15, r = o & 32767, co = r >> 8, ci = r & 255;
    float w = W2[(co * 256 + ci) * 3 + tap];
    float h = (float)(_Float16)w;
    _Float16 hv = (_Float16)(h * 2048.0f);
    _Float16 mv = (_Float16)((w - h) * 2048.0f);
    u16 hb, mb;
    __builtin_memcpy(&hb, &hv, 2);
    __builtin_memcpy(&mb, &mv, 2);
    int c = ci >> 5, cl = ci & 31;
    A2c[(((c * 2 + 0) * 3 + tap) * 128 + co) * 32 + cl] = hb;
    A2c[(((c * 2 + 1) * 3 + tap) * 128 + co) * 32 + cl] = mb;
  }
  int o2 = o - 98304;  // W3: (tap, co, ci), 3*64*128
  if (o2 >= 0 && o2 < 24576) {
    int tap = o2 >> 13, r = o2 & 8191, co = r >> 7, ci = r & 127;
    float w = W3[(co * 128 + ci) * 3 + tap];
    float h = (float)(_Float16)w;
    _Float16 hv = (_Float16)(h * 2048.0f);
    _Float16 mv = (_Float16)((w - h) * 2048.0f);
    u16 hb, mb;
    __builtin_memcpy(&hb, &hv, 2);
    __builtin_memcpy(&mb, &mv, 2);
    int c = ci >> 5, cl = ci & 31;
    A3c[(((c * 2 + 0) * 3 + tap) * 64 + co) * 32 + cl] = hb;
    A3c[(((c * 2 + 1) * 3 + tap) * 64 + co) * 32 + cl] = mb;
  }
  int o3 = o - (98304 + 24576);
  if (o3 >= 0 && o3 < 25600) {
    int f = o3 / 100, i = o3 % 100;
    fw1T[o3] = fw1[i * 256 + f];
  }
  int o4 = o - (98304 + 24576 + 25600);
  if (o4 >= 0 && o4 < 4000) {
    int i = o4 / 40, j = o4 % 40;
    fw2T[o4] = fw2[j * 100 + i];
  }
}

// ---------------------------------------------------------------------------
// conv1 (2->256, K=5, pad=2) + LIF1; writes byte-transposed spikes
// SBT2[b][l][g][t] (byte = spikes of co in [8g,8g+8), bit j = co 8g+j).
// ---------------------------------------------------------------------------
__global__ __launch_bounds__(256) void conv1_lif_kernel(
    const float* __restrict__ x, const float* __restrict__ W1,
    const float* __restrict__ b1, u8* __restrict__ SBT2) {
  __shared__ float xl[2][132];
  __shared__ u16 bl[8][128];
  int b = blockIdx.x, g = blockIdx.y;
  int tid = threadIdx.x;
  for (int i = tid; i < 264; i += 256) {
    int ci = i / 132, idx = i % 132, lg = idx - 2;
    xl[ci][idx] = (lg >= 0 && lg < 128) ? x[(b * 2 + ci) * 128 + lg] : 0.0f;
  }
  __syncthreads();
  int cosub = tid >> 5, tx = tid & 31;
  int co = g * 8 + cosub;
  float w[2][5];
#pragma unroll
  for (int ci = 0; ci < 2; ++ci)
#pragma unroll
    for (int k = 0; k < 5; ++k) w[ci][k] = W1[(co * 2 + ci) * 5 + k];
  float bias = b1[co];
  float cur[4];
#pragma unroll
  for (int j = 0; j < 4; ++j) {
    float acc = bias;
#pragma unroll
    for (int ci = 0; ci < 2; ++ci)
#pragma unroll
      for (int k = 0; k < 5; ++k) acc += w[ci][k] * xl[ci][4 * tx + j + k];
    cur[j] = acc;
  }
  float m[4] = {0.f, 0.f, 0.f, 0.f}, sp[4] = {0.f, 0.f, 0.f, 0.f};
  uint32_t bits[4] = {0u, 0u, 0u, 0u};
#pragma unroll
  for (int t = 0; t < 16; ++t) {
#pragma unroll
    for (int j = 0; j < 4; ++j) {
      m[j] = BETA * m[j] + cur[j] - sp[j];
      bool s = m[j] > 1.0f;
      bits[j] |= ((uint32_t)s) << t;
      sp[j] = s ? 1.0f : 0.0f;
    }
  }
#pragma unroll
  for (int j = 0; j < 4; ++j) bl[cosub][4 * tx + j] = (u16)bits[j];
  __syncthreads();
  if (tid < 128) {
    int l = tid;
    uint32_t wv[8];
#pragma unroll
    for (int j = 0; j < 8; ++j) wv[j] = bl[j][l];
    uint32_t ov[4];
#pragma unroll
    for (int k = 0; k < 4; ++k) {
      uint32_t v = 0;
#pragma unroll
      for (int tt = 0; tt < 4; ++tt) {
        int t = k * 4 + tt;
        uint32_t by = 0;
#pragma unroll
        for (int j = 0; j < 8; ++j) by |= ((wv[j] >> t) & 1u) << j;
        v |= by << (8 * tt);
      }
      ov[k] = v;
    }
    *(uint4*)(SBT2 + ((size_t)(b * 128 + l) * 32 + g) * 16) =
        make_uint4(ov[0], ov[1], ov[2], ov[3]);
  }
}

// ---------------------------------------------------------------------------
// MFMA conv (CIN->COUT, K=3, pad=1) + LIF.
// A: async double-buffered LDS, one barrier per part (copy issued a full part
//    ahead of its drain). B: byte loads from SBT + in-register expansion,
//    one expansion per physical chunk (scale folded into A).
// Block: b x 8 l x all COUT; waves 2x2 (wy m-half, wx 4-l half); nt=4.
// Epilogue: scr transpose -> LIF -> bl LDS -> coalesced 16B stores
// (SBTOUT: byte-transposed layout; else u16-word rows).
// ---------------------------------------------------------------------------
template <int CIN, int COUT, bool SBTOUT>
__global__ __launch_bounds__(256, 3) void conv_mfma_kernel(
    const u8* __restrict__ SBT, const u16* __restrict__ Agc,
    const float* __restrict__ bias, void* __restrict__ outp) {
  constexpr int NPHYS = CIN / 32;
  constexpr int NVIRT = 2 * NPHYS;
  constexpr int MT = COUT / 32;
  constexpr int GB = CIN / 8;
  constexpr int ABYTES = 3 * COUT * 32 * 2;
  constexpr int AW = ABYTES / 4;
  constexpr int AISS = AW / 1024;
  constexpr int EPB = 18432 + COUT * 8 * 2;
  constexpr int LDSSZ = (2 * ABYTES > EPB) ? 2 * ABYTES : EPB;
  __shared__ __align__(16) char lds[LDSSZ];

  int b = blockIdx.x, lb = blockIdx.y * 8;
  int tid = threadIdx.x, lane = tid & 63, wid = tid >> 6;
  int wx = wid & 1, wy = wid >> 1;
  int q = lane >> 4, xx = lane & 15;
  int mbase = wy * (COUT / 2);
  int lw = lb + wx * 4;

  f32x4 acc[MT][4];
#pragma unroll
  for (int mt = 0; mt < MT; ++mt)
#pragma unroll
    for (int nt = 0; nt < 4; ++nt) acc[mt][nt] = (f32x4){0.f, 0.f, 0.f, 0.f};

  // prologue: bytes for phys chunk 0, async copy for virtual part 0
  uint32_t byt[6];
#pragma unroll
  for (int u = 0; u < 6; ++u) {
    int l_in = lw + u - 1;
    byt[u] = ((unsigned)l_in < 128u)
                 ? (uint32_t)SBT[((size_t)(b * 128 + l_in) * GB + q) * 16 + xx]
                 : 0u;
  }
  {
    const char* gsrc = (const char*)Agc + (size_t)wid * AW + lane * 16;
    char* ldst = lds + wid * AW;
#pragma unroll
    for (int i = 0; i < AISS; ++i) async_copy16(gsrc + i * 1024, ldst + i * 1024);
  }

  f16x8 Bf[6];
#pragma unroll 2
  for (int v = 0; v < NVIRT; ++v) {
    __syncthreads();  // drains copy v (issued one full part earlier)
    if (v + 1 < NVIRT) {
      const char* gsrc = (const char*)Agc + (size_t)(v + 1) * ABYTES +
                         (size_t)wid * AW + lane * 16;
      char* ldst = lds + ((v + 1) & 1) * ABYTES + wid * AW;
#pragma unroll
      for (int i = 0; i < AISS; ++i) async_copy16(gsrc + i * 1024, ldst + i * 1024);
    }
    if ((v & 1) == 0) {
#pragma unroll
      for (int u = 0; u < 6; ++u) Bf[u] = expandB(byt[u]);
      int pn = (v >> 1) + 1;
      if (pn < NPHYS) {
#pragma unroll
        for (int u = 0; u < 6; ++u) {
          int l_in = lw + u - 1;
          byt[u] = ((unsigned)l_in < 128u)
                       ? (uint32_t)SBT[((size_t)(b * 128 + l_in) * GB + pn * 4 + q) * 16 + xx]
                       : 0u;
        }
      }
    }
    const u16* Asv = (const u16*)(lds + (v & 1) * ABYTES);
#pragma unroll
    for (int tap = 0; tap < 3; ++tap)
#pragma unroll
      for (int mt = 0; mt < MT; ++mt) {
        f16x8 Af = *(const f16x8*)(Asv + ((size_t)(tap * COUT + mbase + mt * 16 + xx)) * 32 + q * 8);
#pragma unroll
        for (int nt = 0; nt < 4; ++nt)
          acc[mt][nt] = __builtin_amdgcn_mfma_f32_16x16x32_f16(
              Af, Bf[nt + tap], acc[mt][nt], 0, 0, 0);
      }
  }
  __syncthreads();

  // epilogue: per-wave scr transpose -> LIF -> bl -> coalesced stores
  float* scr = (float*)(void*)lds + wid * 1152;  // 4608 B per wave
  u16* bl = (u16*)(lds + 18432);                 // [COUT][8] l-local words
#pragma unroll
  for (int mt = 0; mt < MT; ++mt) {
#pragma unroll
    for (int nt = 0; nt < 4; ++nt)
#pragma unroll
      for (int r = 0; r < 4; ++r)
        scr[(nt * 16 + q * 4 + r) * 18 + xx] = acc[mt][nt][r];
    __syncthreads();
    int co = mbase + mt * 16 + xx;
    float bc = bias[co];
    const float* rowp = scr + (q * 16 + xx) * 18;
    float mm = 0.f, sp = 0.f;
    uint32_t bits = 0;
#pragma unroll
    for (int t = 0; t < 16; ++t) {
      float cur = rowp[t] + bc;
      mm = BETA * mm + cur - sp;
      bool s = mm > 1.0f;
      bits |= ((uint32_t)s) << t;
      sp = s ? 1.0f : 0.0f;
    }
    bl[co * 8 + wx * 4 + q] = (u16)bits;
    __syncthreads();
  }

  if constexpr (SBTOUT) {
    constexpr int GBo = COUT / 8;
    if (tid < GBo * 8) {
      int g = tid & (GBo - 1), ll = tid / GBo;
      uint32_t wv[8];
#pragma unroll
      for (int j = 0; j < 8; ++j) wv[j] = bl[(8 * g + j) * 8 + ll];
      uint32_t ov[4];
#pragma unroll
      for (int k = 0; k < 4; ++k) {
        uint32_t v = 0;
#pragma unroll
        for (int tt = 0; tt < 4; ++tt) {
          int t = k * 4 + tt;
          uint32_t by = 0;
#pragma unroll
          for (int j = 0; j < 8; ++j) by |= ((wv[j] >> t) & 1u) << j;
          v |= by << (8 * tt);
        }
        ov[k] = v;
      }
      *(uint4*)((u8*)outp + ((size_t)(b * 128 + lb + ll) * GBo + g) * 16) =
          make_uint4(ov[0], ov[1], ov[2], ov[3]);
    }
  } else {
    if (tid < COUT) {
      uint4 v = *(const uint4*)(bl + tid * 8);
      *(uint4*)((u16*)outp + ((size_t)b * COUT + tid) * 128 + lb) = v;
    }
  }
}

// ---------------------------------------------------------------------------
// head: conv4 (64->2) + LIF4, fc1 (256->100) + LIF5, fc2 accumulated (popcount)
// ---------------------------------------------------------------------------
__global__ __launch_bounds__(256) void head_kernel(
    const u16* __restrict__ s3bits, const float* __restrict__ W4,
    const float* __restrict__ b4, const float* __restrict__ fw1T,
    const float* __restrict__ fb1, const float* __restrict__ fw2T,
    const float* __restrict__ fb2, float* __restrict__ out) {
  __shared__ u16 s3l[64][130];
  __shared__ float W4l[384];
  __shared__ u16 flat4[256];
  __shared__ u16 s5b[100];
  int b = blockIdx.x, tid = threadIdx.x;

  for (int i = tid; i < 64 * 130; i += 256) {
    int ci = i / 130, idx = i % 130, lg = idx - 1;
    s3l[ci][idx] = (lg >= 0 && lg < 128) ? s3bits[((size_t)b * 64 + ci) * 128 + lg] : (u16)0;
  }
  for (int i = tid; i < 384; i += 256) W4l[i] = W4[i];
  __syncthreads();

  {
    int co = tid >> 7, l = tid & 127;
    float acc4[16];
#pragma unroll
    for (int t = 0; t < 16; ++t) acc4[t] = 0.f;
    for (int ci = 0; ci < 64; ++ci) {
#pragma unroll
      for (int k = 0; k < 3; ++k) {
        float wv = W4l[(co * 64 + ci) * 3 + k];
        uint32_t msk = s3l[ci][l + k];
#pragma unroll
        for (int t = 0; t < 16; ++t)
          acc4[t] = fmaf(wv, (float)((msk >> t) & 1u), acc4[t]);
      }
    }
    float bc = b4[co];
    float m = 0.f, sp = 0.f;
    uint32_t bits = 0;
#pragma unroll
    for (int t = 0; t < 16; ++t) {
      m = BETA * m + (acc4[t] + bc) - sp;
      bool s = m > 1.0f;
      bits |= ((uint32_t)s) << t;
      sp = s ? 1.0f : 0.0f;
    }
    flat4[tid] = (u16)bits;
  }
  __syncthreads();

  if (tid < 100) {
    float acc5[16];
#pragma unroll
    for (int t = 0; t < 16; ++t) acc5[t] = 0.f;
    for (int f = 0; f < 256; ++f) {
      float wv = fw1T[f * 100 + tid];
      uint32_t msk = flat4[f];
#pragma unroll
      for (int t = 0; t < 16; ++t)
        acc5[t] = fmaf(wv, (float)((msk >> t) & 1u), acc5[t]);
    }
    float bc = fb1[tid];
    float m = 0.f, sp = 0.f;
    uint32_t bits = 0;
#pragma unroll
    for (int t = 0; t < 16; ++t) {
      m = BETA * m + (acc5[t] + bc) - sp;
      bool s = m > 1.0f;
      bits |= ((uint32_t)s) << t;
      sp = s ? 1.0f : 0.0f;
    }
    s5b[tid] = (u16)bits;
  }
  __syncthreads();

  if (tid < 40) {
    float a = 0.f;
    for (int i = 0; i < 100; ++i) {
      float wv = fw2T[i * 40 + tid];
      a = fmaf(wv, (float)__popc((uint32_t)s5b[i]), a);
    }
    out[b * 40 + tid] = a * 0.0625f + fb2[tid];
  }
}

// ---------------------------------------------------------------------------
extern "C" void kernel_launch(void* const* d_in, const int* in_sizes, int n_in,
                              void* d_out, int out_size, void* d_ws, size_t ws_size,
                              hipStream_t stream) {
  const float* x   = (const float*)d_in[0];
  const float* W1  = (const float*)d_in[1];
  const float* b1  = (const float*)d_in[2];
  const float* W2  = (const float*)d_in[3];
  const float* b2  = (const float*)d_in[4];
  const float* W3  = (const float*)d_in[5];
  const float* b3  = (const float*)d_in[6];
  const float* W4  = (const float*)d_in[7];
  const float* b4  = (const float*)d_in[8];
  const float* fw1 = (const float*)d_in[9];
  const float* fb1 = (const float*)d_in[10];
  const float* fw2 = (const float*)d_in[11];
  const float* fb2 = (const float*)d_in[12];
  float* out = (float*)d_out;

  char* ws = (char*)d_ws;
  u16*   A2c  = (u16*)(ws);                       // 393216 B [phys][part][tap][co][ci32]
  u16*   A3c  = (u16*)(ws + 393216);              //  98304 B
  float* fw1T = (float*)(ws + 491520);            // 102400 B
  float* fw2T = (float*)(ws + 593920);            //  16000 B (pad to 610304)
  u8*    SBT2 = (u8*)(ws + 610304);               // 134217728 B [b][l][32][16]
  u8*    SBT3 = (u8*)(ws + 610304 + 134217728);   //  67108864 B [b][l][16][16]
  u16*   s3b  = (u16*)(ws + 610304 + 134217728 + 67108864);  // 33554432 B u16 [b][co][l]
  // total: 235,491,328 B

  prep_kernel<<<dim3(596), dim3(256), 0, stream>>>(W2, W3, fw1, fw2, A2c, A3c, fw1T, fw2T);
  conv1_lif_kernel<<<dim3(2048, 32), dim3(256), 0, stream>>>(x, W1, b1, SBT2);
  conv_mfma_kernel<256, 128, true><<<dim3(2048, 16), dim3(256), 0, stream>>>(SBT2, A2c, b2, SBT3);
  conv_mfma_kernel<128, 64, false><<<dim3(2048, 16), dim3(256), 0, stream>>>(SBT3, A3c, b3, s3b);
  head_kernel<<<dim3(2048), dim3(256), 0, stream>>>(s3b, W4, b4, fw1T, fb1, fw2T, fb2, out);
}